// Round 17
// baseline (401.173 us; speedup 1.0000x reference)
//
#include <hip/hip_runtime.h>

#define L 4096
#define HH 64
#define CC 128
#define BB 2

typedef _Float16 f16;
typedef _Float16 f16x8 __attribute__((ext_vector_type(8)));
typedef float f32x4 __attribute__((ext_vector_type(4)));

__device__ __forceinline__ void gl_lds16(const f16* g, f16* l) {
  __builtin_amdgcn_global_load_lds(
      (const __attribute__((address_space(1))) void*)g,
      (__attribute__((address_space(3))) void*)l, 16, 0, 0);
}

// sigma: involution converting row-major flat <-> col-major flat (64x64)
__device__ __forceinline__ int sigma_(int j) { return ((j & 63) << 6) | (j >> 6); }

// full 9-tap fused score from S (reference wrap semantics), scalar (edge columns)
__device__ float fuse9(const f16* __restrict__ Sb, int k, int j) {
  float acc = 0.f;
  int cK = sigma_(k), cQ = sigma_(j);
#pragma unroll
  for (int u = -1; u <= 1; ++u) {
    int a = cK + u, bq = cQ + u;
    if ((unsigned)a < L && (unsigned)bq < L) {
      int r = sigma_(a), c = sigma_(bq);
#pragma unroll
      for (int t = -1; t <= 1; ++t) {
        int rr = r + t, cc = c + t;
        if ((unsigned)rr < L && (unsigned)cc < L) acc += (float)Sb[(size_t)rr * L + cc];
      }
    }
  }
  return acc;
}

// ---------------- kernel 0a: repack [c][u] f32 -> [u][c] f16 (b,f) + fused ssq ----------
__global__ __launch_bounds__(256) void k_repack(
    const float* __restrict__ b, const float* __restrict__ f,
    f16* __restrict__ bT, f16* __restrict__ fT, f16* __restrict__ zp,
    float* __restrict__ ssq) {
  __shared__ float tile[128][65];
  __shared__ float ss[4][64];
  int u0 = blockIdx.x * 64;
  int z = blockIdx.y;            // batch*2 + tensor
  int batch = z >> 1;
  const float* src = ((z & 1) ? f : b) + (size_t)batch * CC * L;
  f16* dst = ((z & 1) ? fT : bT) + (size_t)batch * L * CC;
  int tid = threadIdx.x;
  if (blockIdx.x == 0 && z == 0 && tid < 32) zp[tid] = (f16)0.f;
#pragma unroll
  for (int i = 0; i < 32; ++i) {
    int idx = i * 256 + tid;
    int c = idx >> 6, ux = idx & 63;
    tile[c][ux] = src[(size_t)c * L + u0 + ux];
  }
  __syncthreads();
  if (!(z & 1)) {                // fused ssq for b tensor
    int ux = tid & 63, prt = tid >> 6;
    float s = 0.f;
#pragma unroll 8
    for (int c = prt * 32; c < prt * 32 + 32; ++c) { float v = tile[c][ux]; s += v * v; }
    ss[prt][ux] = s;
  }
#pragma unroll
  for (int j = 0; j < 4; ++j) {
    int t2 = j * 256 + tid;
    int u = t2 >> 4, ch = t2 & 15;
    f16x8 v;
#pragma unroll
    for (int e = 0; e < 8; ++e) v[e] = (f16)tile[ch * 8 + e][u];
    *(f16x8*)(dst + (size_t)(u0 + u) * CC + ch * 8) = v;
  }
  __syncthreads();
  if (!(z & 1) && tid < 64)
    ssq[batch * L + u0 + tid] = ss[0][tid] + ss[1][tid] + ss[2][tid] + ss[3][tid];
}

// ---------------- kernel 0c: inv_n[batch][k] = 1/max(sqrt(sum_{r valid} ssq),1e-4) -------
__global__ void k_norm(const float* __restrict__ ssq, float* __restrict__ inv_n) {
  int gi = blockIdx.x * 256 + threadIdx.x;
  if (gi >= BB * L) return;
  int batch = gi >> 12, k = gi & (L - 1);
  int ky = k >> 6, kx = k & 63;
  float s = 0.f;
#pragma unroll
  for (int dy = -1; dy <= 1; ++dy)
#pragma unroll
    for (int dx = -1; dx <= 1; ++dx) {
      if ((unsigned)(ky + dy) < 64 && (unsigned)(kx + dx) < 64)
        s += ssq[batch * L + k + dy * 64 + dx];
    }
  inv_n[gi] = 1.f / fmaxf(sqrtf(s), 1e-4f);
}

// ---------------- kernel 1b: shifted+masked f16 copies of b (vectorized) -----------------
__global__ __launch_bounds__(256) void k_prep_bm(const float* __restrict__ b, f16* __restrict__ bm) {
  int idx = blockIdx.x * 256 + threadIdx.x;  // x8 elements
  int e8 = idx * 8;
  int k0 = e8 & (L - 1);
  int c = (e8 >> 12) & (CC - 1);
  int bt = e8 >> 19;            // tap*2 + batch
  int batch = bt & 1;
  int tap = bt >> 1;
  int di = 1 - (tap >> 1), dj = 1 - (tap & 1);
  int ky = k0 >> 6, kx0 = k0 & 63;
  const float* src = b + ((size_t)batch * CC + c) * L + k0 + di * 64 + dj;
  bool rowok = (ky + di) < 64;
  f16x8 v;
#pragma unroll
  for (int e = 0; e < 8; ++e) {
    float x = (rowok && (kx0 + e + dj) < 64) ? src[e] : 0.f;
    v[e] = (f16)x;
  }
  *(f16x8*)(bm + (size_t)e8) = v;
}

// ---------------- kernel 1c: mask validity mm[k] + fused per-8-chunk zcnt ---------------
__global__ void k_prep_mm(const float* __restrict__ mask, float* __restrict__ mmv,
                          float* __restrict__ zcnt) {
  __shared__ float sm[256];
  int tid = threadIdx.x;
  int k = blockIdx.x * 256 + tid;
  int ky = k >> 6, kx = k & 63;
  float s = 0.f;
  for (int i = 0; i < 3; ++i)
    for (int j = 0; j < 3; ++j) {
      int yy = ky + i - 1, xx = kx + j - 1;
      if (yy >= 0 && yy < 64 && xx >= 0 && xx < 64) s += mask[yy * 64 + xx];
    }
  float v = (s == 0.f) ? 1.f : 0.f;
  mmv[k] = v;
  sm[tid] = v;
  __syncthreads();
  if (tid < 32) {
    float c = 0.f;
#pragma unroll
    for (int r = 0; r < 8; ++r) c += (sm[tid * 8 + r] == 0.f) ? 1.f : 0.f;
    zcnt[blockIdx.x * 32 + tid] = c;
  }
}

// ---------------- kernel 2: implicit-patch scores GEMM, wide wave tile -------------------
// 128x128 block, 4 waves = (wr, h): 64 rows x 128 cols x one 32-ch k-half per wave.
// Per step: af[4]+bf[8]=12 ds_read_b128 for 32 MFMAs (2.67 MFMA/read vs 2.0 before).
// Epilogue: h=1 waves dump f32 partials to LDS; h=0 adds, applies inv_n, writes S.
__global__ __launch_bounds__(256) void k_gemm_scores(
    const f16* __restrict__ bT, const f16* __restrict__ fT,
    const float* __restrict__ inv_n, const f16* __restrict__ zp,
    f16* __restrict__ S) {
  __shared__ f16 As[2][128 * 64];
  __shared__ f16 Bs[2][128 * 64];
  int qt = blockIdx.x, kt = blockIdx.y, batch = blockIdx.z;
  int tid = threadIdx.x, wid = tid >> 6, lane = tid & 63;
  int wr = wid >> 1, h = wid & 1;
  const f16* A0 = bT + (size_t)batch * L * CC;
  const f16* B0 = fT + (size_t)batch * L * CC;
  f32x4 acc[4][8] = {};
  int rA = wr * 64 + (lane & 15);
  int rB = lane & 15;
  int cb = h * 4 + (lane >> 4);                    // fixed k-half chunk per wave

  const f16* baseA_[4]; const f16* baseB_[4];
  int offL_[4];
  unsigned mA_[4], mB_[4];
#pragma unroll
  for (int i = 0; i < 4; ++i) {
    int chunk = (i * 4 + wid) * 64 + lane;         // 0..1023
    int row = chunk >> 3;                          // 0..127
    int lg = (lane & 7) ^ (row & 7);               // pre-swizzled source chunk
    int k = kt * 128 + row;
    int q = qt * 128 + row;
    baseA_[i] = A0 + (size_t)k * CC + lg * 8;
    baseB_[i] = B0 + (size_t)q * CC + lg * 8;
    offL_[i] = chunk * 8;
    int ky = k >> 6, kx = k & 63, qy = q >> 6, qx = q & 63;
    unsigned ma = 0, mb = 0;
#pragma unroll
    for (int rr = 0; rr < 9; ++rr) {
      int dy = rr / 3 - 1, dx = rr - (rr / 3) * 3 - 1;
      if ((unsigned)(ky + dy) < 64u && (unsigned)(kx + dx) < 64u) ma |= 1u << rr;
      if ((unsigned)(qy + dy) < 64u && (unsigned)(qx + dx) < 64u) mb |= 1u << rr;
    }
    mA_[i] = ma; mB_[i] = mb;
  }

#define STAGE_T(tt, bsel)                                                     \
  do {                                                                        \
    int rr_ = (tt) >> 1, half_ = (tt) & 1;                                    \
    int dy_ = rr_ / 3 - 1, dx_ = rr_ - (rr_ / 3) * 3 - 1;                     \
    int doff_ = (dy_ * 64 + dx_) * CC + half_ * 64;                           \
    _Pragma("unroll")                                                         \
    for (int i = 0; i < 4; ++i) {                                             \
      gl_lds16(((mA_[i] >> rr_) & 1u) ? (baseA_[i] + doff_) : zp,             \
               &As[bsel][0] + offL_[i]);                                      \
      gl_lds16(((mB_[i] >> rr_) & 1u) ? (baseB_[i] + doff_) : zp,             \
               &Bs[bsel][0] + offL_[i]);                                      \
    }                                                                         \
  } while (0)

  STAGE_T(0, 0);
  int cur = 0;
#pragma unroll 1
  for (int t = 0; t < 18; ++t) {
    __syncthreads();
    if (t < 17) STAGE_T(t + 1, cur ^ 1);
    const f16* Ab = &As[cur][0];
    const f16* Bb = &Bs[cur][0];
    f16x8 af[4];
#pragma unroll
    for (int m = 0; m < 4; ++m) {
      int row = rA + m * 16;
      af[m] = *(const f16x8*)(Ab + row * 64 + ((cb ^ (row & 7)) * 8));
    }
#pragma unroll
    for (int n = 0; n < 8; ++n) {
      int row = rB + n * 16;
      f16x8 bf = *(const f16x8*)(Bb + row * 64 + ((cb ^ (row & 7)) * 8));
#pragma unroll
      for (int m = 0; m < 4; ++m)
        acc[m][n] = __builtin_amdgcn_mfma_f32_16x16x32_f16(af[m], bf, acc[m][n], 0, 0, 0);
    }
    cur ^= 1;
  }
#undef STAGE_T

  // epilogue: cross-wave reduce over h (wr=0 -> As, wr=1 -> Bs; 32KB each = 64x128 f32)
  __syncthreads();
  float* red = (wr == 0) ? (float*)&As[0][0] : (float*)&Bs[0][0];
  int rloc = (lane >> 4) * 4;
  int cloc = lane & 15;
  if (h == 1) {
#pragma unroll
    for (int m = 0; m < 4; ++m)
#pragma unroll
      for (int n = 0; n < 8; ++n)
#pragma unroll
        for (int r = 0; r < 4; ++r)
          red[(m * 16 + rloc + r) * 128 + n * 16 + cloc] = acc[m][n][r];
  }
  __syncthreads();
  if (h == 0) {
    f16* Srow = S + (size_t)batch * L * L;
    int kbase = kt * 128 + wr * 64 + rloc;
    int qbase = qt * 128 + cloc;
#pragma unroll
    for (int m = 0; m < 4; ++m) {
      f32x4 invv = *(const f32x4*)(inv_n + (size_t)batch * L + kbase + m * 16);
#pragma unroll
      for (int r = 0; r < 4; ++r) {
        f16* dst = Srow + (size_t)(kbase + m * 16 + r) * L + qbase;
#pragma unroll
        for (int n = 0; n < 8; ++n) {
          float v = acc[m][n][r] + red[(m * 16 + rloc + r) * 128 + n * 16 + cloc];
          dst[n * 16] = (f16)(v * invv[r]);
        }
      }
    }
  }
}

// ---------------- kernel 3: stencil -> PT[q][k] f16 + raw chunk stats --------------------
__global__ __launch_bounds__(256) void k_fuse_stats(
    const f16* __restrict__ S, const float* __restrict__ mmv,
    f16* __restrict__ PT, float* __restrict__ pmP, float* __restrict__ pl) {
  int tid = threadIdx.x;
  int wave = tid >> 6, lane = tid & 63;
  int g = blockIdx.x * 64 + lane;          // q-group 0..511 (494 active)
  if (g >= 494) return;
  int kb = blockIdx.y, batch = blockIdx.z;
  int q0 = 72 + g * 8;                     // aligned, fully interior group
  int k0 = kb * 32 + wave * 8;
  const f16* Sb = S + (size_t)batch * L * L;
  f16* Pb = PT + (size_t)batch * L * L;
  float lg[8][8];
  float m8[8];
#pragma unroll
  for (int e = 0; e < 8; ++e) m8[e] = -3.0e38f;
  unsigned vmask = 0;
#pragma unroll
  for (int kk = 0; kk < 8; ++kk) {
    int k = k0 + kk;
    if (mmv[k] == 0.f) continue;
    vmask |= 1u << kk;
    float acc[8] = {0.f, 0.f, 0.f, 0.f, 0.f, 0.f, 0.f, 0.f};
    int cK = sigma_(k);
#pragma unroll
    for (int u = -1; u <= 1; ++u) {
      int a = cK + u;
      if ((unsigned)a >= L) continue;
      int r = sigma_(a);                   // = k + 64u for interior k
      const f16* cb = Sb + (size_t)r * L + (q0 + 64 * u);
      {
        f16x8 v = *(const f16x8*)cb;
#pragma unroll
        for (int e = 0; e < 8; ++e) acc[e] += (float)v[e];
      }
      if (r >= 1) {
        const f16* rm = cb - L;
        f16x8 v = *(const f16x8*)rm;
        acc[0] += (float)rm[-1];
#pragma unroll
        for (int e = 1; e < 8; ++e) acc[e] += (float)v[e - 1];
      }
      if (r <= L - 2) {
        const f16* rp = cb + L;
        f16x8 v = *(const f16x8*)rp;
#pragma unroll
        for (int e = 0; e < 7; ++e) acc[e] += (float)v[e + 1];
        acc[7] += (float)rp[8];
      }
    }
#pragma unroll
    for (int e = 0; e < 8; ++e) {
      float x = acc[e] * 10.f;
      lg[kk][e] = x;
      m8[e] = fmaxf(m8[e], x);
    }
  }
  float l8[8] = {0.f, 0.f, 0.f, 0.f, 0.f, 0.f, 0.f, 0.f};
#pragma unroll
  for (int kk = 0; kk < 8; ++kk) {
    if ((vmask >> kk) & 1u) {
#pragma unroll
      for (int e = 0; e < 8; ++e) {
        float p = __expf(lg[kk][e] - m8[e]);
        l8[e] += p;
        lg[kk][e] = p;
      }
    } else {
#pragma unroll
      for (int e = 0; e < 8; ++e) lg[kk][e] = 0.f;
    }
  }
#pragma unroll
  for (int e = 0; e < 8; ++e) {
    f16 v[8];
#pragma unroll
    for (int kk = 0; kk < 8; ++kk) v[kk] = (f16)lg[kk][e];
    *(f16x8*)(Pb + (size_t)(q0 + e) * L + k0) = *(f16x8*)v;
  }
  int ck = kb * 4 + wave;
  float* pmp = pmP + (size_t)ck * (BB * L) + (size_t)batch * L + q0;
  float* plp = pl + (size_t)ck * (BB * L) + (size_t)batch * L + q0;
  *(f32x4*)pmp = *(f32x4*)&m8[0]; *(f32x4*)(pmp + 4) = *(f32x4*)&m8[4];
  *(f32x4*)plp = *(f32x4*)&l8[0]; *(f32x4*)(plp + 4) = *(f32x4*)&l8[4];
}

// ---------------- kernel 3e: edge q columns (144 cols), one 8-k chunk per block ----------
__global__ __launch_bounds__(256) void k_fuse_stats_edge(
    const f16* __restrict__ S, const float* __restrict__ mmv,
    f16* __restrict__ PT, float* __restrict__ pmP, float* __restrict__ pl) {
  int tid = threadIdx.x;
  if (tid >= 144) return;
  int q = (tid < 72) ? tid : (4024 + tid - 72);
  int ck = blockIdx.x, batch = blockIdx.y;
  int k0 = ck * 8;
  const f16* Sb = S + (size_t)batch * L * L;
  f16* Pb = PT + (size_t)batch * L * L;
  float lgs[8];
  float m = -3.0e38f;
  unsigned vmask = 0;
#pragma unroll
  for (int kk = 0; kk < 8; ++kk) {
    int k = k0 + kk;
    if (mmv[k] == 0.f) continue;
    vmask |= 1u << kk;
    float x = 10.f * fuse9(Sb, k, q);
    lgs[kk] = x;
    m = fmaxf(m, x);
  }
  float l = 0.f;
  f16 v[8];
#pragma unroll
  for (int kk = 0; kk < 8; ++kk) {
    if ((vmask >> kk) & 1u) {
      float p = __expf(lgs[kk] - m);
      l += p;
      v[kk] = (f16)p;
    } else {
      v[kk] = (f16)0.f;
    }
  }
  *(f16x8*)(Pb + (size_t)q * L + k0) = *(f16x8*)v;
  pmP[(size_t)ck * (BB * L) + (size_t)batch * L + q] = m;
  pl[(size_t)ck * (BB * L) + (size_t)batch * L + q] = l;
}

// ---------------- kernel 3b: combine raw partials + masked-count fold --------------------
__global__ __launch_bounds__(256) void k_softmax_reduce(
    const float* __restrict__ pmP, const float* __restrict__ pl,
    const float* __restrict__ zcnt,
    float* __restrict__ Mq, float* __restrict__ invLq) {
  __shared__ float sm[4][64], sl[4][64];
  int tid = threadIdx.x;
  int ql = tid & 63, part = tid >> 6;
  int qi = blockIdx.x * 64 + ql;
  float m = -3.0e38f, l = 0.f;
  int i0 = part * 128;
  float cntp = 0.f;
#pragma unroll 4
  for (int i = i0; i < i0 + 128; ++i) {
    float pmv = pmP[(size_t)i * (BB * L) + qi];
    float plv = pl[(size_t)i * (BB * L) + qi];
    float nm = fmaxf(m, pmv);
    l = l * __expf(m - nm) + plv * __expf(pmv - nm);
    m = nm;
    cntp += zcnt[i & 511];
  }
  if (cntp > 0.f) {
    float nm = fmaxf(m, 0.f);
    l = l * __expf(m - nm) + cntp * __expf(-nm);
    m = nm;
  }
  sm[part][ql] = m; sl[part][ql] = l;
  __syncthreads();
  if (part == 0) {
    float M = sm[0][ql];
#pragma unroll
    for (int p = 1; p < 4; ++p) M = fmaxf(M, sm[p][ql]);
    float Ls = 0.f;
#pragma unroll
    for (int p = 0; p < 4; ++p) Ls += sl[p][ql] * __expf(sm[p][ql] - M);
    Mq[qi] = M;
    invLq[qi] = 1.f / Ls;
  }
}

// ---------------- kernel 5: aggregation; Bt = PT(f16) * exp(pmP - M) * iL ----------------
__global__ __launch_bounds__(512) void k_agg(
    const f16* __restrict__ PT, const float* __restrict__ pmP,
    const float* __restrict__ Mq, const float* __restrict__ invLq,
    const f16* __restrict__ bm, float* __restrict__ part) {
  __shared__ f16 Asm[512 * 32];   // [R=tap*128+c][32kk], chunk-swizzled
  __shared__ f16 Bt[136 * 40];    // [pp][kk], kk-chunk swizzled: phys = kg ^ ((pp>>3)&3)
  int pt = blockIdx.x, ks = blockIdx.y, batch = blockIdx.z;
  int p0 = pt * 64;
  int tid = threadIdx.x, wid = tid >> 6, lane = tid & 63;
  int wr = wid >> 1, wc = wid & 1;
  const f16* Pb = PT + (size_t)batch * L * L;

  // ---- hoisted A staging state ----
  const f16* gA_[4]; f16* lA_[4];
#pragma unroll
  for (int i = 0; i < 4; ++i) {
    int R = wid * 64 + i * 16 + (lane >> 2);
    int tap = R >> 7, c = R & 127;
    int chl = (lane & 3) ^ ((R >> 1) & 3);
    gA_[i] = bm + (((size_t)(tap * 2 + batch) * CC + c) * L) + chl * 8;
    lA_[i] = Asm + R * 32 + (lane & 3) * 8;
  }

  // ---- hoisted B-task state: tau -> (kg = tau&3, pp = tau>>2); 544 tasks ----
  bool act1 = (tid < 32);
  int kg_[2]; bool qok_[2]; float M_[2], iL_[2];
  const f16* ptb_[2]; f16* bw_[2];
  size_t bq_[2];
#pragma unroll
  for (int s = 0; s < 2; ++s) {
    int tau = tid + s * 512;
    int kgv = tau & 3, ppv = tau >> 2;
    if (tau >= 544) { ppv = 0; kgv = 0; }
    kg_[s] = kgv;
    int q = p0 + ppv;
    bool qok = q < L;
    int qc = qok ? q : (L - 1);
    qok_[s] = qok;
    M_[s] = Mq[(size_t)batch * L + qc];
    iL_[s] = invLq[(size_t)batch * L + qc];
    ptb_[s] = Pb + (size_t)qc * L + kgv * 8;
    bq_[s] = (size_t)batch * L + qc;
    bw_[s] = Bt + ppv * 40 + ((kgv ^ ((ppv >> 3) & 3)) * 8);
  }

  f16x8 vv_[2];
  int kend = ks * 512 + 512;

#define LOADB(K0)                                                             \
  do {                                                                        \
    _Pragma("unroll")                                                         \
    for (int s = 0; s < 2; ++s) {                                             \
      if (s == 1 && !act1) break;                                             \
      f16x8 pv = *(const f16x8*)(ptb_[s] + (K0));                             \
      int ck = ((K0) >> 3) + kg_[s];                                          \
      float pmv = pmP[(size_t)ck * (BB * L) + bq_[s]];                        \
      float corr = qok_[s] ? __expf(pmv - M_[s]) * iL_[s] : 0.f;              \
      f16 v[8];                                                               \
      _Pragma("unroll")                                                       \
      for (int j = 0; j < 8; ++j) v[j] = (f16)((float)pv[j] * corr);          \
      vv_[s] = *(f16x8*)v;                                                    \
    }                                                                         \
  } while (0)

  LOADB(ks * 512);                // prologue
  f32x4 acc[2][2] = {};
#pragma unroll 1
  for (int k0 = ks * 512; k0 < kend; k0 += 32) {
    __syncthreads();              // prior MFMA done reading Asm/Bt
    *(f16x8*)bw_[0] = vv_[0];
    if (act1) *(f16x8*)bw_[1] = vv_[1];
#pragma unroll
    for (int i = 0; i < 4; ++i) gl_lds16(gA_[i] + k0, lA_[i]);
    __syncthreads();              // drains ds_writes + gl_lds
#pragma unroll
    for (int tap = 0; tap < 4; ++tap) {
      int dlt = (tap >> 1) * 64 + (tap & 1);
      f16x8 af[2], bf[2];
#pragma unroll
      for (int m = 0; m < 2; ++m) {
        int R = tap * 128 + wr * 32 + m * 16 + (lane & 15);
        int ph = (lane >> 4) ^ ((R >> 1) & 3);
        af[m] = *(const f16x8*)(Asm + R * 32 + ph * 8);
      }
#pragma unroll
      for (int n = 0; n < 2; ++n) {
        int pp = wc * 32 + n * 16 + (lane & 15) + dlt;
        int ph = (lane >> 4) ^ ((pp >> 3) & 3);
        bf[n] = *(const f16x8*)(Bt + pp * 40 + ph * 8);
      }
#pragma unroll
      for (int m = 0; m < 2; ++m)
#pragma unroll
        for (int n = 0; n < 2; ++n)
          acc[m][n] = __builtin_amdgcn_mfma_f32_16x16x32_f16(af[m], bf[n], acc[m][n], 0, 0, 0);
    }
    if (k0 + 32 < kend) LOADB(k0 + 32);
  }
#undef LOADB

  int cb = wr * 32 + (lane >> 4) * 4;
  int pb = p0 + wc * 32 + (lane & 15);
#pragma unroll
  for (int m = 0; m < 2; ++m)
#pragma unroll
    for (int n = 0; n < 2; ++n)
#pragma unroll
      for (int r = 0; r < 4; ++r) {
        int c = cb + m * 16 + r;
        int p = pb + n * 16;
        part[(((size_t)ks * 2 + batch) * CC + c) * L + p] = acc[m][n][r];
      }
}

// ---------------- kernel 5b: sum 8 K-split partials, scale, border mask ------------------
__global__ __launch_bounds__(256) void k_agg_reduce(const float* __restrict__ part, float* __restrict__ out) {
  int idx = (blockIdx.x * 256 + threadIdx.x) * 4;   // 2*128*4096 total
  f32x4 s = {0.f, 0.f, 0.f, 0.f};
#pragma unroll
  for (int ks = 0; ks < 8; ++ks) {
    f32x4 v = *(const f32x4*)(part + (size_t)ks * (2 * CC * L) + idx);
#pragma unroll
    for (int e = 0; e < 4; ++e) s[e] += v[e];
  }
  int p = idx & (L - 1);
  int u = p >> 6, vv = p & 63;
  f32x4 o;
#pragma unroll
  for (int e = 0; e < 4; ++e) o[e] = (u < 63 && (vv + e) < 63) ? s[e] * 0.25f : 0.f;
  *(f32x4*)(out + idx) = o;
}

extern "C" void kernel_launch(void* const* d_in, const int* in_sizes, int n_in,
                              void* d_out, int out_size, void* d_ws, size_t ws_size,
                              hipStream_t stream) {
  const float* f = (const float*)d_in[0];
  const float* b = (const float*)d_in[1];
  const float* mask = (const float*)d_in[2];
  float* out = (float*)d_out;
  char* ws = (char*)d_ws;

  f16* PT    = (f16*)(ws + 0);             // 67,108,864
  f16* S     = (f16*)(ws + 67108864);      // 67,108,864
  f16* bm    = (f16*)(ws + 134217728);     // 8,388,608
  float* pmP = (float*)(ws + 142606336);   // 16,777,216
  float* pl  = (float*)(ws + 159383552);   // 16,777,216
  float* part= (float*)(ws + 176160768);   // 33,554,432 (8 ks-splits)
  float* mmv = (float*)(ws + 209715200);   // 16,384
  float* Mq  = (float*)(ws + 209731584);   // 32,768
  float* iLq = (float*)(ws + 209764352);   // 32,768
  f16* bT    = (f16*)(ws + 209797120);     // 2,097,152
  f16* fT    = (f16*)(ws + 211894272);     // 2,097,152
  float* ssq = (float*)(ws + 213991424);   // 32,768
  float* invn= (float*)(ws + 214024192);   // 32,768
  f16* zp    = (f16*)(ws + 214056960);     // 64
  float* zcnt= (float*)(ws + 214057088);   // 2,048

  k_repack<<<dim3(64, 4), dim3(256), 0, stream>>>(b, f, bT, fT, zp, ssq);
  k_norm<<<dim3(32), dim3(256), 0, stream>>>(ssq, invn);
  k_prep_bm<<<dim3(2048), dim3(256), 0, stream>>>(b, bm);
  k_prep_mm<<<dim3(16), dim3(256), 0, stream>>>(mask, mmv, zcnt);
  k_gemm_scores<<<dim3(32, 32, 2), dim3(256), 0, stream>>>(bT, fT, invn, zp, S);
  k_fuse_stats<<<dim3(8, 128, 2), dim3(256), 0, stream>>>(S, mmv, PT, pmP, pl);
  k_fuse_stats_edge<<<dim3(512, 2), dim3(256), 0, stream>>>(S, mmv, PT, pmP, pl);
  k_softmax_reduce<<<dim3(128), dim3(256), 0, stream>>>(pmP, pl, zcnt, Mq, iLq);
  k_agg<<<dim3(64, 8, 2), dim3(512), 0, stream>>>(PT, pmP, Mq, iLq, bm, part);
  k_agg_reduce<<<dim3(1024), dim3(256), 0, stream>>>(part, out);
}

// Round 18
// 317.148 us; speedup vs baseline: 1.2649x; 1.2649x over previous
//
#include <hip/hip_runtime.h>

#define L 4096
#define HH 64
#define CC 128
#define BB 2

typedef _Float16 f16;
typedef _Float16 f16x8 __attribute__((ext_vector_type(8)));
typedef float f32x4 __attribute__((ext_vector_type(4)));

__device__ __forceinline__ void gl_lds16(const f16* g, f16* l) {
  __builtin_amdgcn_global_load_lds(
      (const __attribute__((address_space(1))) void*)g,
      (__attribute__((address_space(3))) void*)l, 16, 0, 0);
}

// sigma: involution converting row-major flat <-> col-major flat (64x64)
__device__ __forceinline__ int sigma_(int j) { return ((j & 63) << 6) | (j >> 6); }

// full 9-tap fused score from S (reference wrap semantics), scalar (edge columns)
__device__ float fuse9(const f16* __restrict__ Sb, int k, int j) {
  float acc = 0.f;
  int cK = sigma_(k), cQ = sigma_(j);
#pragma unroll
  for (int u = -1; u <= 1; ++u) {
    int a = cK + u, bq = cQ + u;
    if ((unsigned)a < L && (unsigned)bq < L) {
      int r = sigma_(a), c = sigma_(bq);
#pragma unroll
      for (int t = -1; t <= 1; ++t) {
        int rr = r + t, cc = c + t;
        if ((unsigned)rr < L && (unsigned)cc < L) acc += (float)Sb[(size_t)rr * L + cc];
      }
    }
  }
  return acc;
}

// ---------------- kernel 0a: repack [c][u] f32 -> [u][c] f16 (b,f) + fused ssq ----------
__global__ __launch_bounds__(256) void k_repack(
    const float* __restrict__ b, const float* __restrict__ f,
    f16* __restrict__ bT, f16* __restrict__ fT, f16* __restrict__ zp,
    float* __restrict__ ssq) {
  __shared__ float tile[128][65];
  __shared__ float ss[4][64];
  int u0 = blockIdx.x * 64;
  int z = blockIdx.y;            // batch*2 + tensor
  int batch = z >> 1;
  const float* src = ((z & 1) ? f : b) + (size_t)batch * CC * L;
  f16* dst = ((z & 1) ? fT : bT) + (size_t)batch * L * CC;
  int tid = threadIdx.x;
  if (blockIdx.x == 0 && z == 0 && tid < 32) zp[tid] = (f16)0.f;
#pragma unroll
  for (int i = 0; i < 32; ++i) {
    int idx = i * 256 + tid;
    int c = idx >> 6, ux = idx & 63;
    tile[c][ux] = src[(size_t)c * L + u0 + ux];
  }
  __syncthreads();
  if (!(z & 1)) {                // fused ssq for b tensor
    int ux = tid & 63, prt = tid >> 6;
    float s = 0.f;
#pragma unroll 8
    for (int c = prt * 32; c < prt * 32 + 32; ++c) { float v = tile[c][ux]; s += v * v; }
    ss[prt][ux] = s;
  }
#pragma unroll
  for (int j = 0; j < 4; ++j) {
    int t2 = j * 256 + tid;
    int u = t2 >> 4, ch = t2 & 15;
    f16x8 v;
#pragma unroll
    for (int e = 0; e < 8; ++e) v[e] = (f16)tile[ch * 8 + e][u];
    *(f16x8*)(dst + (size_t)(u0 + u) * CC + ch * 8) = v;
  }
  __syncthreads();
  if (!(z & 1) && tid < 64)
    ssq[batch * L + u0 + tid] = ss[0][tid] + ss[1][tid] + ss[2][tid] + ss[3][tid];
}

// ---------------- kernel 0c: inv_n[batch][k] = 1/max(sqrt(sum_{r valid} ssq),1e-4) -------
__global__ void k_norm(const float* __restrict__ ssq, float* __restrict__ inv_n) {
  int gi = blockIdx.x * 256 + threadIdx.x;
  if (gi >= BB * L) return;
  int batch = gi >> 12, k = gi & (L - 1);
  int ky = k >> 6, kx = k & 63;
  float s = 0.f;
#pragma unroll
  for (int dy = -1; dy <= 1; ++dy)
#pragma unroll
    for (int dx = -1; dx <= 1; ++dx) {
      if ((unsigned)(ky + dy) < 64 && (unsigned)(kx + dx) < 64)
        s += ssq[batch * L + k + dy * 64 + dx];
    }
  inv_n[gi] = 1.f / fmaxf(sqrtf(s), 1e-4f);
}

// ---------------- kernel 1b: shifted+masked f16 copies of b (vectorized) -----------------
__global__ __launch_bounds__(256) void k_prep_bm(const float* __restrict__ b, f16* __restrict__ bm) {
  int idx = blockIdx.x * 256 + threadIdx.x;  // x8 elements
  int e8 = idx * 8;
  int k0 = e8 & (L - 1);
  int c = (e8 >> 12) & (CC - 1);
  int bt = e8 >> 19;            // tap*2 + batch
  int batch = bt & 1;
  int tap = bt >> 1;
  int di = 1 - (tap >> 1), dj = 1 - (tap & 1);
  int ky = k0 >> 6, kx0 = k0 & 63;
  const float* src = b + ((size_t)batch * CC + c) * L + k0 + di * 64 + dj;
  bool rowok = (ky + di) < 64;
  f16x8 v;
#pragma unroll
  for (int e = 0; e < 8; ++e) {
    float x = (rowok && (kx0 + e + dj) < 64) ? src[e] : 0.f;
    v[e] = (f16)x;
  }
  *(f16x8*)(bm + (size_t)e8) = v;
}

// ---------------- kernel 1c: mask validity mm[k] + fused per-8-chunk zcnt ---------------
__global__ void k_prep_mm(const float* __restrict__ mask, float* __restrict__ mmv,
                          float* __restrict__ zcnt) {
  __shared__ float sm[256];
  int tid = threadIdx.x;
  int k = blockIdx.x * 256 + tid;
  int ky = k >> 6, kx = k & 63;
  float s = 0.f;
  for (int i = 0; i < 3; ++i)
    for (int j = 0; j < 3; ++j) {
      int yy = ky + i - 1, xx = kx + j - 1;
      if (yy >= 0 && yy < 64 && xx >= 0 && xx < 64) s += mask[yy * 64 + xx];
    }
  float v = (s == 0.f) ? 1.f : 0.f;
  mmv[k] = v;
  sm[tid] = v;
  __syncthreads();
  if (tid < 32) {
    float c = 0.f;
#pragma unroll
    for (int r = 0; r < 8; ++r) c += (sm[tid * 8 + r] == 0.f) ? 1.f : 0.f;
    zcnt[blockIdx.x * 32 + tid] = c;
  }
}

// ---------------- kernel 2: implicit-patch scores GEMM, 2-phase double-buffered ----------
__global__ __launch_bounds__(256) void k_gemm_scores(
    const f16* __restrict__ bT, const f16* __restrict__ fT,
    const float* __restrict__ inv_n, const f16* __restrict__ zp,
    f16* __restrict__ S) {
  __shared__ f16 As[2][128 * 64];
  __shared__ f16 Bs[2][128 * 64];
  int qt = blockIdx.x, kt = blockIdx.y, batch = blockIdx.z;
  int tid = threadIdx.x, wid = tid >> 6, lane = tid & 63;
  int wr = wid >> 1, wc = wid & 1;
  const f16* A0 = bT + (size_t)batch * L * CC;
  const f16* B0 = fT + (size_t)batch * L * CC;
  f32x4 acc[4][4] = {};
  int rA = wr * 64 + (lane & 15);
  int rB = wc * 64 + (lane & 15);

  const f16* baseA_[4]; const f16* baseB_[4];
  int offL_[4];
  unsigned mA_[4], mB_[4];
#pragma unroll
  for (int i = 0; i < 4; ++i) {
    int chunk = (i * 4 + wid) * 64 + lane;         // 0..1023
    int row = chunk >> 3;                          // 0..127
    int lg = (lane & 7) ^ (row & 7);               // pre-swizzled source chunk
    int k = kt * 128 + row;
    int q = qt * 128 + row;
    baseA_[i] = A0 + (size_t)k * CC + lg * 8;
    baseB_[i] = B0 + (size_t)q * CC + lg * 8;
    offL_[i] = chunk * 8;
    int ky = k >> 6, kx = k & 63, qy = q >> 6, qx = q & 63;
    unsigned ma = 0, mb = 0;
#pragma unroll
    for (int rr = 0; rr < 9; ++rr) {
      int dy = rr / 3 - 1, dx = rr - (rr / 3) * 3 - 1;
      if ((unsigned)(ky + dy) < 64u && (unsigned)(kx + dx) < 64u) ma |= 1u << rr;
      if ((unsigned)(qy + dy) < 64u && (unsigned)(qx + dx) < 64u) mb |= 1u << rr;
    }
    mA_[i] = ma; mB_[i] = mb;
  }

#define STAGE_T(tt, bsel)                                                     \
  do {                                                                        \
    int rr_ = (tt) >> 1, half_ = (tt) & 1;                                    \
    int dy_ = rr_ / 3 - 1, dx_ = rr_ - (rr_ / 3) * 3 - 1;                     \
    int doff_ = (dy_ * 64 + dx_) * CC + half_ * 64;                           \
    _Pragma("unroll")                                                         \
    for (int i = 0; i < 4; ++i) {                                             \
      gl_lds16(((mA_[i] >> rr_) & 1u) ? (baseA_[i] + doff_) : zp,             \
               &As[bsel][0] + offL_[i]);                                      \
      gl_lds16(((mB_[i] >> rr_) & 1u) ? (baseB_[i] + doff_) : zp,             \
               &Bs[bsel][0] + offL_[i]);                                      \
    }                                                                         \
  } while (0)

  STAGE_T(0, 0);
  int cur = 0;
#pragma unroll 1
  for (int t = 0; t < 18; ++t) {
    __syncthreads();
    if (t < 17) STAGE_T(t + 1, cur ^ 1);
    const f16* Ab = &As[cur][0];
    const f16* Bb = &Bs[cur][0];
#pragma unroll
    for (int h2 = 0; h2 < 2; ++h2) {
      int cb = h2 * 4 + (lane >> 4);
      f16x8 af[4], bf[4];
#pragma unroll
      for (int m = 0; m < 4; ++m) {
        int row = rA + m * 16;
        af[m] = *(const f16x8*)(Ab + row * 64 + ((cb ^ (row & 7)) * 8));
      }
#pragma unroll
      for (int n = 0; n < 4; ++n) {
        int row = rB + n * 16;
        bf[n] = *(const f16x8*)(Bb + row * 64 + ((cb ^ (row & 7)) * 8));
      }
#pragma unroll
      for (int m = 0; m < 4; ++m)
#pragma unroll
        for (int n = 0; n < 4; ++n)
          acc[m][n] = __builtin_amdgcn_mfma_f32_16x16x32_f16(af[m], bf[n], acc[m][n], 0, 0, 0);
    }
    cur ^= 1;
  }
#undef STAGE_T

  f16* Srow = S + (size_t)batch * L * L;
  int kbase = kt * 128 + wr * 64 + (lane >> 4) * 4;
  int qbase = qt * 128 + wc * 64 + (lane & 15);
#pragma unroll
  for (int m = 0; m < 4; ++m) {
    f32x4 invv = *(const f32x4*)(inv_n + (size_t)batch * L + kbase + m * 16);
#pragma unroll
    for (int r = 0; r < 4; ++r) {
      f16* dst = Srow + (size_t)(kbase + m * 16 + r) * L + qbase;
#pragma unroll
      for (int n = 0; n < 4; ++n) dst[n * 16] = (f16)(acc[m][n][r] * invv[r]);
    }
  }
}

// ---------------- kernel 3: stencil -> PT[q][k] f16 + raw chunk stats --------------------
__global__ __launch_bounds__(256) void k_fuse_stats(
    const f16* __restrict__ S, const float* __restrict__ mmv,
    f16* __restrict__ PT, float* __restrict__ pmP, float* __restrict__ pl) {
  int tid = threadIdx.x;
  int wave = tid >> 6, lane = tid & 63;
  int g = blockIdx.x * 64 + lane;          // q-group 0..511 (494 active)
  if (g >= 494) return;
  int kb = blockIdx.y, batch = blockIdx.z;
  int q0 = 72 + g * 8;                     // aligned, fully interior group
  int k0 = kb * 32 + wave * 8;
  const f16* Sb = S + (size_t)batch * L * L;
  f16* Pb = PT + (size_t)batch * L * L;
  float lg[8][8];
  float m8[8];
#pragma unroll
  for (int e = 0; e < 8; ++e) m8[e] = -3.0e38f;
  unsigned vmask = 0;
#pragma unroll
  for (int kk = 0; kk < 8; ++kk) {
    int k = k0 + kk;
    if (mmv[k] == 0.f) continue;
    vmask |= 1u << kk;
    float acc[8] = {0.f, 0.f, 0.f, 0.f, 0.f, 0.f, 0.f, 0.f};
    int cK = sigma_(k);
#pragma unroll
    for (int u = -1; u <= 1; ++u) {
      int a = cK + u;
      if ((unsigned)a >= L) continue;
      int r = sigma_(a);                   // = k + 64u for interior k
      const f16* cb = Sb + (size_t)r * L + (q0 + 64 * u);
      {
        f16x8 v = *(const f16x8*)cb;
#pragma unroll
        for (int e = 0; e < 8; ++e) acc[e] += (float)v[e];
      }
      if (r >= 1) {
        const f16* rm = cb - L;
        f16x8 v = *(const f16x8*)rm;
        acc[0] += (float)rm[-1];
#pragma unroll
        for (int e = 1; e < 8; ++e) acc[e] += (float)v[e - 1];
      }
      if (r <= L - 2) {
        const f16* rp = cb + L;
        f16x8 v = *(const f16x8*)rp;
#pragma unroll
        for (int e = 0; e < 7; ++e) acc[e] += (float)v[e + 1];
        acc[7] += (float)rp[8];
      }
    }
#pragma unroll
    for (int e = 0; e < 8; ++e) {
      float x = acc[e] * 10.f;
      lg[kk][e] = x;
      m8[e] = fmaxf(m8[e], x);
    }
  }
  float l8[8] = {0.f, 0.f, 0.f, 0.f, 0.f, 0.f, 0.f, 0.f};
#pragma unroll
  for (int kk = 0; kk < 8; ++kk) {
    if ((vmask >> kk) & 1u) {
#pragma unroll
      for (int e = 0; e < 8; ++e) {
        float p = __expf(lg[kk][e] - m8[e]);
        l8[e] += p;
        lg[kk][e] = p;
      }
    } else {
#pragma unroll
      for (int e = 0; e < 8; ++e) lg[kk][e] = 0.f;
    }
  }
#pragma unroll
  for (int e = 0; e < 8; ++e) {
    f16 v[8];
#pragma unroll
    for (int kk = 0; kk < 8; ++kk) v[kk] = (f16)lg[kk][e];
    *(f16x8*)(Pb + (size_t)(q0 + e) * L + k0) = *(f16x8*)v;
  }
  int ck = kb * 4 + wave;
  float* pmp = pmP + (size_t)ck * (BB * L) + (size_t)batch * L + q0;
  float* plp = pl + (size_t)ck * (BB * L) + (size_t)batch * L + q0;
  *(f32x4*)pmp = *(f32x4*)&m8[0]; *(f32x4*)(pmp + 4) = *(f32x4*)&m8[4];
  *(f32x4*)plp = *(f32x4*)&l8[0]; *(f32x4*)(plp + 4) = *(f32x4*)&l8[4];
}

// ---------------- kernel 3e: edge q columns (144 cols), one 8-k chunk per block ----------
__global__ __launch_bounds__(256) void k_fuse_stats_edge(
    const f16* __restrict__ S, const float* __restrict__ mmv,
    f16* __restrict__ PT, float* __restrict__ pmP, float* __restrict__ pl) {
  int tid = threadIdx.x;
  if (tid >= 144) return;
  int q = (tid < 72) ? tid : (4024 + tid - 72);
  int ck = blockIdx.x, batch = blockIdx.y;
  int k0 = ck * 8;
  const f16* Sb = S + (size_t)batch * L * L;
  f16* Pb = PT + (size_t)batch * L * L;
  float lgs[8];
  float m = -3.0e38f;
  unsigned vmask = 0;
#pragma unroll
  for (int kk = 0; kk < 8; ++kk) {
    int k = k0 + kk;
    if (mmv[k] == 0.f) continue;
    vmask |= 1u << kk;
    float x = 10.f * fuse9(Sb, k, q);
    lgs[kk] = x;
    m = fmaxf(m, x);
  }
  float l = 0.f;
  f16 v[8];
#pragma unroll
  for (int kk = 0; kk < 8; ++kk) {
    if ((vmask >> kk) & 1u) {
      float p = __expf(lgs[kk] - m);
      l += p;
      v[kk] = (f16)p;
    } else {
      v[kk] = (f16)0.f;
    }
  }
  *(f16x8*)(Pb + (size_t)q * L + k0) = *(f16x8*)v;
  pmP[(size_t)ck * (BB * L) + (size_t)batch * L + q] = m;
  pl[(size_t)ck * (BB * L) + (size_t)batch * L + q] = l;
}

// ---------------- kernel 3b: combine raw partials + masked-count fold --------------------
__global__ __launch_bounds__(256) void k_softmax_reduce(
    const float* __restrict__ pmP, const float* __restrict__ pl,
    const float* __restrict__ zcnt,
    float* __restrict__ Mq, float* __restrict__ invLq) {
  __shared__ float sm[4][64], sl[4][64];
  int tid = threadIdx.x;
  int ql = tid & 63, part = tid >> 6;
  int qi = blockIdx.x * 64 + ql;
  float m = -3.0e38f, l = 0.f;
  int i0 = part * 128;
  float cntp = 0.f;
#pragma unroll 4
  for (int i = i0; i < i0 + 128; ++i) {
    float pmv = pmP[(size_t)i * (BB * L) + qi];
    float plv = pl[(size_t)i * (BB * L) + qi];
    float nm = fmaxf(m, pmv);
    l = l * __expf(m - nm) + plv * __expf(pmv - nm);
    m = nm;
    cntp += zcnt[i & 511];
  }
  if (cntp > 0.f) {
    float nm = fmaxf(m, 0.f);
    l = l * __expf(m - nm) + cntp * __expf(-nm);
    m = nm;
  }
  sm[part][ql] = m; sl[part][ql] = l;
  __syncthreads();
  if (part == 0) {
    float M = sm[0][ql];
#pragma unroll
    for (int p = 1; p < 4; ++p) M = fmaxf(M, sm[p][ql]);
    float Ls = 0.f;
#pragma unroll
    for (int p = 0; p < 4; ++p) Ls += sl[p][ql] * __expf(sm[p][ql] - M);
    Mq[qi] = M;
    invLq[qi] = 1.f / Ls;
  }
}

// ---------------- kernel 5: aggregation; Bt = PT(f16) * exp(pmP - M) * iL ----------------
__global__ __launch_bounds__(512) void k_agg(
    const f16* __restrict__ PT, const float* __restrict__ pmP,
    const float* __restrict__ Mq, const float* __restrict__ invLq,
    const f16* __restrict__ bm, float* __restrict__ part) {
  __shared__ f16 Asm[512 * 32];   // [R=tap*128+c][32kk], chunk-swizzled
  __shared__ f16 Bt[136 * 40];    // [pp][kk], kk-chunk swizzled: phys = kg ^ ((pp>>3)&3)
  int pt = blockIdx.x, ks = blockIdx.y, batch = blockIdx.z;
  int p0 = pt * 64;
  int tid = threadIdx.x, wid = tid >> 6, lane = tid & 63;
  int wr = wid >> 1, wc = wid & 1;
  const f16* Pb = PT + (size_t)batch * L * L;

  // ---- hoisted A staging state ----
  const f16* gA_[4]; f16* lA_[4];
#pragma unroll
  for (int i = 0; i < 4; ++i) {
    int R = wid * 64 + i * 16 + (lane >> 2);
    int tap = R >> 7, c = R & 127;
    int chl = (lane & 3) ^ ((R >> 1) & 3);
    gA_[i] = bm + (((size_t)(tap * 2 + batch) * CC + c) * L) + chl * 8;
    lA_[i] = Asm + R * 32 + (lane & 3) * 8;
  }

  // ---- hoisted B-task state: tau -> (kg = tau&3, pp = tau>>2); 544 tasks ----
  bool act1 = (tid < 32);
  int kg_[2]; bool qok_[2]; float M_[2], iL_[2];
  const f16* ptb_[2]; f16* bw_[2];
  size_t bq_[2];
#pragma unroll
  for (int s = 0; s < 2; ++s) {
    int tau = tid + s * 512;
    int kgv = tau & 3, ppv = tau >> 2;
    if (tau >= 544) { ppv = 0; kgv = 0; }
    kg_[s] = kgv;
    int q = p0 + ppv;
    bool qok = q < L;
    int qc = qok ? q : (L - 1);
    qok_[s] = qok;
    M_[s] = Mq[(size_t)batch * L + qc];
    iL_[s] = invLq[(size_t)batch * L + qc];
    ptb_[s] = Pb + (size_t)qc * L + kgv * 8;
    bq_[s] = (size_t)batch * L + qc;
    bw_[s] = Bt + ppv * 40 + ((kgv ^ ((ppv >> 3) & 3)) * 8);
  }

  f16x8 vv_[2];
  int kend = ks * 512 + 512;

#define LOADB(K0)                                                             \
  do {                                                                        \
    _Pragma("unroll")                                                         \
    for (int s = 0; s < 2; ++s) {                                             \
      if (s == 1 && !act1) break;                                             \
      f16x8 pv = *(const f16x8*)(ptb_[s] + (K0));                             \
      int ck = ((K0) >> 3) + kg_[s];                                          \
      float pmv = pmP[(size_t)ck * (BB * L) + bq_[s]];                        \
      float corr = qok_[s] ? __expf(pmv - M_[s]) * iL_[s] : 0.f;              \
      f16 v[8];                                                               \
      _Pragma("unroll")                                                       \
      for (int j = 0; j < 8; ++j) v[j] = (f16)((float)pv[j] * corr);          \
      vv_[s] = *(f16x8*)v;                                                    \
    }                                                                         \
  } while (0)

  LOADB(ks * 512);                // prologue
  f32x4 acc[2][2] = {};
#pragma unroll 1
  for (int k0 = ks * 512; k0 < kend; k0 += 32) {
    __syncthreads();              // prior MFMA done reading Asm/Bt
    *(f16x8*)bw_[0] = vv_[0];
    if (act1) *(f16x8*)bw_[1] = vv_[1];
#pragma unroll
    for (int i = 0; i < 4; ++i) gl_lds16(gA_[i] + k0, lA_[i]);
    __syncthreads();              // drains ds_writes + gl_lds
#pragma unroll
    for (int tap = 0; tap < 4; ++tap) {
      int dlt = (tap >> 1) * 64 + (tap & 1);
      f16x8 af[2], bf[2];
#pragma unroll
      for (int m = 0; m < 2; ++m) {
        int R = tap * 128 + wr * 32 + m * 16 + (lane & 15);
        int ph = (lane >> 4) ^ ((R >> 1) & 3);
        af[m] = *(const f16x8*)(Asm + R * 32 + ph * 8);
      }
#pragma unroll
      for (int n = 0; n < 2; ++n) {
        int pp = wc * 32 + n * 16 + (lane & 15) + dlt;
        int ph = (lane >> 4) ^ ((pp >> 3) & 3);
        bf[n] = *(const f16x8*)(Bt + pp * 40 + ph * 8);
      }
#pragma unroll
      for (int m = 0; m < 2; ++m)
#pragma unroll
        for (int n = 0; n < 2; ++n)
          acc[m][n] = __builtin_amdgcn_mfma_f32_16x16x32_f16(af[m], bf[n], acc[m][n], 0, 0, 0);
    }
    if (k0 + 32 < kend) LOADB(k0 + 32);
  }
#undef LOADB

  int cb = wr * 32 + (lane >> 4) * 4;
  int pb = p0 + wc * 32 + (lane & 15);
#pragma unroll
  for (int m = 0; m < 2; ++m)
#pragma unroll
    for (int n = 0; n < 2; ++n)
#pragma unroll
      for (int r = 0; r < 4; ++r) {
        int c = cb + m * 16 + r;
        int p = pb + n * 16;
        part[(((size_t)ks * 2 + batch) * CC + c) * L + p] = acc[m][n][r];
      }
}

// ---------------- kernel 5b: sum 8 K-split partials, scale, border mask ------------------
__global__ __launch_bounds__(256) void k_agg_reduce(const float* __restrict__ part, float* __restrict__ out) {
  int idx = (blockIdx.x * 256 + threadIdx.x) * 4;   // 2*128*4096 total
  f32x4 s = {0.f, 0.f, 0.f, 0.f};
#pragma unroll
  for (int ks = 0; ks < 8; ++ks) {
    f32x4 v = *(const f32x4*)(part + (size_t)ks * (2 * CC * L) + idx);
#pragma unroll
    for (int e = 0; e < 4; ++e) s[e] += v[e];
  }
  int p = idx & (L - 1);
  int u = p >> 6, vv = p & 63;
  f32x4 o;
#pragma unroll
  for (int e = 0; e < 4; ++e) o[e] = (u < 63 && (vv + e) < 63) ? s[e] * 0.25f : 0.f;
  *(f32x4*)(out + idx) = o;
}

extern "C" void kernel_launch(void* const* d_in, const int* in_sizes, int n_in,
                              void* d_out, int out_size, void* d_ws, size_t ws_size,
                              hipStream_t stream) {
  const float* f = (const float*)d_in[0];
  const float* b = (const float*)d_in[1];
  const float* mask = (const float*)d_in[2];
  float* out = (float*)d_out;
  char* ws = (char*)d_ws;

  f16* PT    = (f16*)(ws + 0);             // 67,108,864
  f16* S     = (f16*)(ws + 67108864);      // 67,108,864
  f16* bm    = (f16*)(ws + 134217728);     // 8,388,608
  float* pmP = (float*)(ws + 142606336);   // 16,777,216
  float* pl  = (float*)(ws + 159383552);   // 16,777,216
  float* part= (float*)(ws + 176160768);   // 33,554,432 (8 ks-splits)
  float* mmv = (float*)(ws + 209715200);   // 16,384
  float* Mq  = (float*)(ws + 209731584);   // 32,768
  float* iLq = (float*)(ws + 209764352);   // 32,768
  f16* bT    = (f16*)(ws + 209797120);     // 2,097,152
  f16* fT    = (f16*)(ws + 211894272);     // 2,097,152
  float* ssq = (float*)(ws + 213991424);   // 32,768
  float* invn= (float*)(ws + 214024192);   // 32,768
  f16* zp    = (f16*)(ws + 214056960);     // 64
  float* zcnt= (float*)(ws + 214057088);   // 2,048

  k_repack<<<dim3(64, 4), dim3(256), 0, stream>>>(b, f, bT, fT, zp, ssq);
  k_norm<<<dim3(32), dim3(256), 0, stream>>>(ssq, invn);
  k_prep_bm<<<dim3(2048), dim3(256), 0, stream>>>(b, bm);
  k_prep_mm<<<dim3(16), dim3(256), 0, stream>>>(mask, mmv, zcnt);
  k_gemm_scores<<<dim3(32, 32, 2), dim3(256), 0, stream>>>(bT, fT, invn, zp, S);
  k_fuse_stats<<<dim3(8, 128, 2), dim3(256), 0, stream>>>(S, mmv, PT, pmP, pl);
  k_fuse_stats_edge<<<dim3(512, 2), dim3(256), 0, stream>>>(S, mmv, PT, pmP, pl);
  k_softmax_reduce<<<dim3(128), dim3(256), 0, stream>>>(pmP, pl, zcnt, Mq, iLq);
  k_agg<<<dim3(64, 8, 2), dim3(512), 0, stream>>>(PT, pmP, Mq, iLq, bm, part);
  k_agg_reduce<<<dim3(1024), dim3(256), 0, stream>>>(part, out);
}

// Round 19
// 315.197 us; speedup vs baseline: 1.2728x; 1.0062x over previous
//
#include <hip/hip_runtime.h>

#define L 4096
#define HH 64
#define CC 128
#define BB 2

typedef _Float16 f16;
typedef _Float16 f16x8 __attribute__((ext_vector_type(8)));
typedef float f32x4 __attribute__((ext_vector_type(4)));

__device__ __forceinline__ void gl_lds16(const f16* g, f16* l) {
  __builtin_amdgcn_global_load_lds(
      (const __attribute__((address_space(1))) void*)g,
      (__attribute__((address_space(3))) void*)l, 16, 0, 0);
}

// sigma: involution converting row-major flat <-> col-major flat (64x64)
__device__ __forceinline__ int sigma_(int j) { return ((j & 63) << 6) | (j >> 6); }

// full 9-tap fused score from S (reference wrap semantics), scalar (edge columns)
__device__ float fuse9(const f16* __restrict__ Sb, int k, int j) {
  float acc = 0.f;
  int cK = sigma_(k), cQ = sigma_(j);
#pragma unroll
  for (int u = -1; u <= 1; ++u) {
    int a = cK + u, bq = cQ + u;
    if ((unsigned)a < L && (unsigned)bq < L) {
      int r = sigma_(a), c = sigma_(bq);
#pragma unroll
      for (int t = -1; t <= 1; ++t) {
        int rr = r + t, cc = c + t;
        if ((unsigned)rr < L && (unsigned)cc < L) acc += (float)Sb[(size_t)rr * L + cc];
      }
    }
  }
  return acc;
}

// ---------------- kernel 0a: repack [c][u] f32 -> [u][c] f16 (b,f) + fused ssq ----------
__global__ __launch_bounds__(256) void k_repack(
    const float* __restrict__ b, const float* __restrict__ f,
    f16* __restrict__ bT, f16* __restrict__ fT, f16* __restrict__ zp,
    float* __restrict__ ssq) {
  __shared__ float tile[128][65];
  __shared__ float ss[4][64];
  int u0 = blockIdx.x * 64;
  int z = blockIdx.y;            // batch*2 + tensor
  int batch = z >> 1;
  const float* src = ((z & 1) ? f : b) + (size_t)batch * CC * L;
  f16* dst = ((z & 1) ? fT : bT) + (size_t)batch * L * CC;
  int tid = threadIdx.x;
  if (blockIdx.x == 0 && z == 0 && tid < 32) zp[tid] = (f16)0.f;
#pragma unroll
  for (int i = 0; i < 32; ++i) {
    int idx = i * 256 + tid;
    int c = idx >> 6, ux = idx & 63;
    tile[c][ux] = src[(size_t)c * L + u0 + ux];
  }
  __syncthreads();
  if (!(z & 1)) {                // fused ssq for b tensor
    int ux = tid & 63, prt = tid >> 6;
    float s = 0.f;
#pragma unroll 8
    for (int c = prt * 32; c < prt * 32 + 32; ++c) { float v = tile[c][ux]; s += v * v; }
    ss[prt][ux] = s;
  }
#pragma unroll
  for (int j = 0; j < 4; ++j) {
    int t2 = j * 256 + tid;
    int u = t2 >> 4, ch = t2 & 15;
    f16x8 v;
#pragma unroll
    for (int e = 0; e < 8; ++e) v[e] = (f16)tile[ch * 8 + e][u];
    *(f16x8*)(dst + (size_t)(u0 + u) * CC + ch * 8) = v;
  }
  __syncthreads();
  if (!(z & 1) && tid < 64)
    ssq[batch * L + u0 + tid] = ss[0][tid] + ss[1][tid] + ss[2][tid] + ss[3][tid];
}

// ---------------- kernel 0c: inv_n[batch][k] = 1/max(sqrt(sum_{r valid} ssq),1e-4) -------
__global__ void k_norm(const float* __restrict__ ssq, float* __restrict__ inv_n) {
  int gi = blockIdx.x * 256 + threadIdx.x;
  if (gi >= BB * L) return;
  int batch = gi >> 12, k = gi & (L - 1);
  int ky = k >> 6, kx = k & 63;
  float s = 0.f;
#pragma unroll
  for (int dy = -1; dy <= 1; ++dy)
#pragma unroll
    for (int dx = -1; dx <= 1; ++dx) {
      if ((unsigned)(ky + dy) < 64 && (unsigned)(kx + dx) < 64)
        s += ssq[batch * L + k + dy * 64 + dx];
    }
  inv_n[gi] = 1.f / fmaxf(sqrtf(s), 1e-4f);
}

// ---------------- kernel 1b: shifted+masked f16 copies of b (vectorized) -----------------
__global__ __launch_bounds__(256) void k_prep_bm(const float* __restrict__ b, f16* __restrict__ bm) {
  int idx = blockIdx.x * 256 + threadIdx.x;  // x8 elements
  int e8 = idx * 8;
  int k0 = e8 & (L - 1);
  int c = (e8 >> 12) & (CC - 1);
  int bt = e8 >> 19;            // tap*2 + batch
  int batch = bt & 1;
  int tap = bt >> 1;
  int di = 1 - (tap >> 1), dj = 1 - (tap & 1);
  int ky = k0 >> 6, kx0 = k0 & 63;
  const float* src = b + ((size_t)batch * CC + c) * L + k0 + di * 64 + dj;
  bool rowok = (ky + di) < 64;
  f16x8 v;
#pragma unroll
  for (int e = 0; e < 8; ++e) {
    float x = (rowok && (kx0 + e + dj) < 64) ? src[e] : 0.f;
    v[e] = (f16)x;
  }
  *(f16x8*)(bm + (size_t)e8) = v;
}

// ---------------- kernel 1c: mask validity mm[k] + fused per-8-chunk zcnt ---------------
__global__ void k_prep_mm(const float* __restrict__ mask, float* __restrict__ mmv,
                          float* __restrict__ zcnt) {
  __shared__ float sm[256];
  int tid = threadIdx.x;
  int k = blockIdx.x * 256 + tid;
  int ky = k >> 6, kx = k & 63;
  float s = 0.f;
  for (int i = 0; i < 3; ++i)
    for (int j = 0; j < 3; ++j) {
      int yy = ky + i - 1, xx = kx + j - 1;
      if (yy >= 0 && yy < 64 && xx >= 0 && xx < 64) s += mask[yy * 64 + xx];
    }
  float v = (s == 0.f) ? 1.f : 0.f;
  mmv[k] = v;
  sm[tid] = v;
  __syncthreads();
  if (tid < 32) {
    float c = 0.f;
#pragma unroll
    for (int r = 0; r < 8; ++r) c += (sm[tid * 8 + r] == 0.f) ? 1.f : 0.f;
    zcnt[blockIdx.x * 32 + tid] = c;
  }
}

// ---------------- kernel 2: implicit-patch scores GEMM, 2-phase double-buffered ----------
__global__ __launch_bounds__(256) void k_gemm_scores(
    const f16* __restrict__ bT, const f16* __restrict__ fT,
    const float* __restrict__ inv_n, const f16* __restrict__ zp,
    f16* __restrict__ S) {
  __shared__ f16 As[2][128 * 64];
  __shared__ f16 Bs[2][128 * 64];
  int qt = blockIdx.x, kt = blockIdx.y, batch = blockIdx.z;
  int tid = threadIdx.x, wid = tid >> 6, lane = tid & 63;
  int wr = wid >> 1, wc = wid & 1;
  const f16* A0 = bT + (size_t)batch * L * CC;
  const f16* B0 = fT + (size_t)batch * L * CC;
  f32x4 acc[4][4] = {};
  int rA = wr * 64 + (lane & 15);
  int rB = wc * 64 + (lane & 15);

  const f16* baseA_[4]; const f16* baseB_[4];
  int offL_[4];
  unsigned mA_[4], mB_[4];
#pragma unroll
  for (int i = 0; i < 4; ++i) {
    int chunk = (i * 4 + wid) * 64 + lane;         // 0..1023
    int row = chunk >> 3;                          // 0..127
    int lg = (lane & 7) ^ (row & 7);               // pre-swizzled source chunk
    int k = kt * 128 + row;
    int q = qt * 128 + row;
    baseA_[i] = A0 + (size_t)k * CC + lg * 8;
    baseB_[i] = B0 + (size_t)q * CC + lg * 8;
    offL_[i] = chunk * 8;
    int ky = k >> 6, kx = k & 63, qy = q >> 6, qx = q & 63;
    unsigned ma = 0, mb = 0;
#pragma unroll
    for (int rr = 0; rr < 9; ++rr) {
      int dy = rr / 3 - 1, dx = rr - (rr / 3) * 3 - 1;
      if ((unsigned)(ky + dy) < 64u && (unsigned)(kx + dx) < 64u) ma |= 1u << rr;
      if ((unsigned)(qy + dy) < 64u && (unsigned)(qx + dx) < 64u) mb |= 1u << rr;
    }
    mA_[i] = ma; mB_[i] = mb;
  }

#define STAGE_T(tt, bsel)                                                     \
  do {                                                                        \
    int rr_ = (tt) >> 1, half_ = (tt) & 1;                                    \
    int dy_ = rr_ / 3 - 1, dx_ = rr_ - (rr_ / 3) * 3 - 1;                     \
    int doff_ = (dy_ * 64 + dx_) * CC + half_ * 64;                           \
    _Pragma("unroll")                                                         \
    for (int i = 0; i < 4; ++i) {                                             \
      gl_lds16(((mA_[i] >> rr_) & 1u) ? (baseA_[i] + doff_) : zp,             \
               &As[bsel][0] + offL_[i]);                                      \
      gl_lds16(((mB_[i] >> rr_) & 1u) ? (baseB_[i] + doff_) : zp,             \
               &Bs[bsel][0] + offL_[i]);                                      \
    }                                                                         \
  } while (0)

  STAGE_T(0, 0);
  int cur = 0;
#pragma unroll 1
  for (int t = 0; t < 18; ++t) {
    __syncthreads();
    if (t < 17) STAGE_T(t + 1, cur ^ 1);
    const f16* Ab = &As[cur][0];
    const f16* Bb = &Bs[cur][0];
#pragma unroll
    for (int h2 = 0; h2 < 2; ++h2) {
      int cb = h2 * 4 + (lane >> 4);
      f16x8 af[4], bf[4];
#pragma unroll
      for (int m = 0; m < 4; ++m) {
        int row = rA + m * 16;
        af[m] = *(const f16x8*)(Ab + row * 64 + ((cb ^ (row & 7)) * 8));
      }
#pragma unroll
      for (int n = 0; n < 4; ++n) {
        int row = rB + n * 16;
        bf[n] = *(const f16x8*)(Bb + row * 64 + ((cb ^ (row & 7)) * 8));
      }
#pragma unroll
      for (int m = 0; m < 4; ++m)
#pragma unroll
        for (int n = 0; n < 4; ++n)
          acc[m][n] = __builtin_amdgcn_mfma_f32_16x16x32_f16(af[m], bf[n], acc[m][n], 0, 0, 0);
    }
    cur ^= 1;
  }
#undef STAGE_T

  f16* Srow = S + (size_t)batch * L * L;
  int kbase = kt * 128 + wr * 64 + (lane >> 4) * 4;
  int qbase = qt * 128 + wc * 64 + (lane & 15);
#pragma unroll
  for (int m = 0; m < 4; ++m) {
    f32x4 invv = *(const f32x4*)(inv_n + (size_t)batch * L + kbase + m * 16);
#pragma unroll
    for (int r = 0; r < 4; ++r) {
      f16* dst = Srow + (size_t)(kbase + m * 16 + r) * L + qbase;
#pragma unroll
      for (int n = 0; n < 4; ++n) dst[n * 16] = (f16)(acc[m][n][r] * invv[r]);
    }
  }
}

// ---------------- kernel 3: stencil -> PT[q][k] f16 + raw chunk stats --------------------
__global__ __launch_bounds__(256) void k_fuse_stats(
    const f16* __restrict__ S, const float* __restrict__ mmv,
    f16* __restrict__ PT, float* __restrict__ pmP, float* __restrict__ pl) {
  int tid = threadIdx.x;
  int wave = tid >> 6, lane = tid & 63;
  int g = blockIdx.x * 64 + lane;          // q-group 0..511 (494 active)
  if (g >= 494) return;
  int kb = blockIdx.y, batch = blockIdx.z;
  int q0 = 72 + g * 8;                     // aligned, fully interior group
  int k0 = kb * 32 + wave * 8;
  const f16* Sb = S + (size_t)batch * L * L;
  f16* Pb = PT + (size_t)batch * L * L;
  float lg[8][8];
  float m8[8];
#pragma unroll
  for (int e = 0; e < 8; ++e) m8[e] = -3.0e38f;
  unsigned vmask = 0;
#pragma unroll
  for (int kk = 0; kk < 8; ++kk) {
    int k = k0 + kk;
    if (mmv[k] == 0.f) continue;
    vmask |= 1u << kk;
    float acc[8] = {0.f, 0.f, 0.f, 0.f, 0.f, 0.f, 0.f, 0.f};
    int cK = sigma_(k);
#pragma unroll
    for (int u = -1; u <= 1; ++u) {
      int a = cK + u;
      if ((unsigned)a >= L) continue;
      int r = sigma_(a);                   // = k + 64u for interior k
      const f16* cb = Sb + (size_t)r * L + (q0 + 64 * u);
      {
        f16x8 v = *(const f16x8*)cb;
#pragma unroll
        for (int e = 0; e < 8; ++e) acc[e] += (float)v[e];
      }
      if (r >= 1) {
        const f16* rm = cb - L;
        f16x8 v = *(const f16x8*)rm;
        acc[0] += (float)rm[-1];
#pragma unroll
        for (int e = 1; e < 8; ++e) acc[e] += (float)v[e - 1];
      }
      if (r <= L - 2) {
        const f16* rp = cb + L;
        f16x8 v = *(const f16x8*)rp;
#pragma unroll
        for (int e = 0; e < 7; ++e) acc[e] += (float)v[e + 1];
        acc[7] += (float)rp[8];
      }
    }
#pragma unroll
    for (int e = 0; e < 8; ++e) {
      float x = acc[e] * 10.f;
      lg[kk][e] = x;
      m8[e] = fmaxf(m8[e], x);
    }
  }
  float l8[8] = {0.f, 0.f, 0.f, 0.f, 0.f, 0.f, 0.f, 0.f};
#pragma unroll
  for (int kk = 0; kk < 8; ++kk) {
    if ((vmask >> kk) & 1u) {
#pragma unroll
      for (int e = 0; e < 8; ++e) {
        float p = __expf(lg[kk][e] - m8[e]);
        l8[e] += p;
        lg[kk][e] = p;
      }
    } else {
#pragma unroll
      for (int e = 0; e < 8; ++e) lg[kk][e] = 0.f;
    }
  }
#pragma unroll
  for (int e = 0; e < 8; ++e) {
    f16 v[8];
#pragma unroll
    for (int kk = 0; kk < 8; ++kk) v[kk] = (f16)lg[kk][e];
    *(f16x8*)(Pb + (size_t)(q0 + e) * L + k0) = *(f16x8*)v;
  }
  int ck = kb * 4 + wave;
  float* pmp = pmP + (size_t)ck * (BB * L) + (size_t)batch * L + q0;
  float* plp = pl + (size_t)ck * (BB * L) + (size_t)batch * L + q0;
  *(f32x4*)pmp = *(f32x4*)&m8[0]; *(f32x4*)(pmp + 4) = *(f32x4*)&m8[4];
  *(f32x4*)plp = *(f32x4*)&l8[0]; *(f32x4*)(plp + 4) = *(f32x4*)&l8[4];
}

// ---------------- kernel 3e: edge q columns (144 cols), one 8-k chunk per block ----------
__global__ __launch_bounds__(256) void k_fuse_stats_edge(
    const f16* __restrict__ S, const float* __restrict__ mmv,
    f16* __restrict__ PT, float* __restrict__ pmP, float* __restrict__ pl) {
  int tid = threadIdx.x;
  if (tid >= 144) return;
  int q = (tid < 72) ? tid : (4024 + tid - 72);
  int ck = blockIdx.x, batch = blockIdx.y;
  int k0 = ck * 8;
  const f16* Sb = S + (size_t)batch * L * L;
  f16* Pb = PT + (size_t)batch * L * L;
  float lgs[8];
  float m = -3.0e38f;
  unsigned vmask = 0;
#pragma unroll
  for (int kk = 0; kk < 8; ++kk) {
    int k = k0 + kk;
    if (mmv[k] == 0.f) continue;
    vmask |= 1u << kk;
    float x = 10.f * fuse9(Sb, k, q);
    lgs[kk] = x;
    m = fmaxf(m, x);
  }
  float l = 0.f;
  f16 v[8];
#pragma unroll
  for (int kk = 0; kk < 8; ++kk) {
    if ((vmask >> kk) & 1u) {
      float p = __expf(lgs[kk] - m);
      l += p;
      v[kk] = (f16)p;
    } else {
      v[kk] = (f16)0.f;
    }
  }
  *(f16x8*)(Pb + (size_t)q * L + k0) = *(f16x8*)v;
  pmP[(size_t)ck * (BB * L) + (size_t)batch * L + q] = m;
  pl[(size_t)ck * (BB * L) + (size_t)batch * L + q] = l;
}

// ---------------- kernel 3b: combine raw partials + masked-count fold --------------------
__global__ __launch_bounds__(256) void k_softmax_reduce(
    const float* __restrict__ pmP, const float* __restrict__ pl,
    const float* __restrict__ zcnt,
    float* __restrict__ Mq, float* __restrict__ invLq) {
  __shared__ float sm[4][64], sl[4][64];
  int tid = threadIdx.x;
  int ql = tid & 63, part = tid >> 6;
  int qi = blockIdx.x * 64 + ql;
  float m = -3.0e38f, l = 0.f;
  int i0 = part * 128;
  float cntp = 0.f;
#pragma unroll 4
  for (int i = i0; i < i0 + 128; ++i) {
    float pmv = pmP[(size_t)i * (BB * L) + qi];
    float plv = pl[(size_t)i * (BB * L) + qi];
    float nm = fmaxf(m, pmv);
    l = l * __expf(m - nm) + plv * __expf(pmv - nm);
    m = nm;
    cntp += zcnt[i & 511];
  }
  if (cntp > 0.f) {
    float nm = fmaxf(m, 0.f);
    l = l * __expf(m - nm) + cntp * __expf(-nm);
    m = nm;
  }
  sm[part][ql] = m; sl[part][ql] = l;
  __syncthreads();
  if (part == 0) {
    float M = sm[0][ql];
#pragma unroll
    for (int p = 1; p < 4; ++p) M = fmaxf(M, sm[p][ql]);
    float Ls = 0.f;
#pragma unroll
    for (int p = 0; p < 4; ++p) Ls += sl[p][ql] * __expf(sm[p][ql] - M);
    Mq[qi] = M;
    invLq[qi] = 1.f / Ls;
  }
}

// ---------------- kernel 5: aggregation; 2-deep pipelined B-load + setprio MFMA ----------
__global__ __launch_bounds__(512) void k_agg(
    const f16* __restrict__ PT, const float* __restrict__ pmP,
    const float* __restrict__ Mq, const float* __restrict__ invLq,
    const f16* __restrict__ bm, float* __restrict__ part) {
  __shared__ f16 Asm[512 * 32];   // [R=tap*128+c][32kk], chunk-swizzled
  __shared__ f16 Bt[136 * 40];    // [pp][kk], kk-chunk swizzled: phys = kg ^ ((pp>>3)&3)
  int pt = blockIdx.x, ks = blockIdx.y, batch = blockIdx.z;
  int p0 = pt * 64;
  int tid = threadIdx.x, wid = tid >> 6, lane = tid & 63;
  int wr = wid >> 1, wc = wid & 1;
  const f16* Pb = PT + (size_t)batch * L * L;

  // ---- hoisted A staging state ----
  const f16* gA_[4]; f16* lA_[4];
#pragma unroll
  for (int i = 0; i < 4; ++i) {
    int R = wid * 64 + i * 16 + (lane >> 2);
    int tap = R >> 7, c = R & 127;
    int chl = (lane & 3) ^ ((R >> 1) & 3);
    gA_[i] = bm + (((size_t)(tap * 2 + batch) * CC + c) * L) + chl * 8;
    lA_[i] = Asm + R * 32 + (lane & 3) * 8;
  }

  // ---- hoisted B-task state: tau -> (kg = tau&3, pp = tau>>2); 544 tasks ----
  bool act1 = (tid < 32);
  int kg_[2]; bool qok_[2]; float M_[2], iL_[2];
  const f16* ptb_[2]; f16* bw_[2];
  size_t bq_[2];
#pragma unroll
  for (int s = 0; s < 2; ++s) {
    int tau = tid + s * 512;
    int kgv = tau & 3, ppv = tau >> 2;
    if (tau >= 544) { ppv = 0; kgv = 0; }
    kg_[s] = kgv;
    int q = p0 + ppv;
    bool qok = q < L;
    int qc = qok ? q : (L - 1);
    qok_[s] = qok;
    M_[s] = Mq[(size_t)batch * L + qc];
    iL_[s] = invLq[(size_t)batch * L + qc];
    ptb_[s] = Pb + (size_t)qc * L + kgv * 8;
    bq_[s] = (size_t)batch * L + qc;
    bw_[s] = Bt + ppv * 40 + ((kgv ^ ((ppv >> 3) & 3)) * 8);
  }

  f16x8 vp0[2], vp1[2];           // 2-deep pipeline register buffers
  int kbase = ks * 512;
  int kend = kbase + 512;

#define LOADB(K0, VB)                                                         \
  do {                                                                        \
    _Pragma("unroll")                                                         \
    for (int s = 0; s < 2; ++s) {                                             \
      if (s == 1 && !act1) break;                                             \
      f16x8 pv = *(const f16x8*)(ptb_[s] + (K0));                             \
      int ck = ((K0) >> 3) + kg_[s];                                          \
      float pmv = pmP[(size_t)ck * (BB * L) + bq_[s]];                        \
      float corr = qok_[s] ? __expf(pmv - M_[s]) * iL_[s] : 0.f;              \
      f16 v[8];                                                               \
      _Pragma("unroll")                                                       \
      for (int j = 0; j < 8; ++j) v[j] = (f16)((float)pv[j] * corr);          \
      VB[s] = *(f16x8*)v;                                                     \
    }                                                                         \
  } while (0)

#define AGG_STEP(K0, VB)                                                      \
  do {                                                                        \
    __syncthreads();              /* prior MFMA done reading Asm/Bt */        \
    *(f16x8*)bw_[0] = VB[0];                                                  \
    if (act1) *(f16x8*)bw_[1] = VB[1];                                        \
    _Pragma("unroll")                                                         \
    for (int i = 0; i < 4; ++i) gl_lds16(gA_[i] + (K0), lA_[i]);              \
    __syncthreads();              /* drains ds_writes + gl_lds */             \
    __builtin_amdgcn_s_setprio(1);                                            \
    _Pragma("unroll")                                                         \
    for (int tap = 0; tap < 4; ++tap) {                                       \
      int dlt = (tap >> 1) * 64 + (tap & 1);                                  \
      f16x8 af[2], bf[2];                                                     \
      _Pragma("unroll")                                                       \
      for (int m = 0; m < 2; ++m) {                                           \
        int R = tap * 128 + wr * 32 + m * 16 + (lane & 15);                   \
        int ph = (lane >> 4) ^ ((R >> 1) & 3);                                \
        af[m] = *(const f16x8*)(Asm + R * 32 + ph * 8);                       \
      }                                                                       \
      _Pragma("unroll")                                                       \
      for (int n = 0; n < 2; ++n) {                                           \
        int pp = wc * 32 + n * 16 + (lane & 15) + dlt;                        \
        int ph = (lane >> 4) ^ ((pp >> 3) & 3);                               \
        bf[n] = *(const f16x8*)(Bt + pp * 40 + ph * 8);                       \
      }                                                                       \
      _Pragma("unroll")                                                       \
      for (int m = 0; m < 2; ++m)                                             \
        _Pragma("unroll")                                                     \
        for (int n = 0; n < 2; ++n)                                           \
          acc[m][n] = __builtin_amdgcn_mfma_f32_16x16x32_f16(af[m], bf[n],    \
                                                             acc[m][n], 0, 0, 0); \
    }                                                                         \
    __builtin_amdgcn_s_setprio(0);                                            \
  } while (0)

  LOADB(kbase, vp0);
  LOADB(kbase + 32, vp1);
  f32x4 acc[2][2] = {};
#pragma unroll 1
  for (int k0 = kbase; k0 < kend; k0 += 64) {
    AGG_STEP(k0, vp0);
    if (k0 + 64 < kend) LOADB(k0 + 64, vp0);     // lands 2 steps ahead
    AGG_STEP(k0 + 32, vp1);
    if (k0 + 96 < kend) LOADB(k0 + 96, vp1);
  }
#undef AGG_STEP
#undef LOADB

  int cb = wr * 32 + (lane >> 4) * 4;
  int pb = p0 + wc * 32 + (lane & 15);
#pragma unroll
  for (int m = 0; m < 2; ++m)
#pragma unroll
    for (int n = 0; n < 2; ++n)
#pragma unroll
      for (int r = 0; r < 4; ++r) {
        int c = cb + m * 16 + r;
        int p = pb + n * 16;
        part[(((size_t)ks * 2 + batch) * CC + c) * L + p] = acc[m][n][r];
      }
}

// ---------------- kernel 5b: sum 8 K-split partials, scale, border mask ------------------
__global__ __launch_bounds__(256) void k_agg_reduce(const float* __restrict__ part, float* __restrict__ out) {
  int idx = (blockIdx.x * 256 + threadIdx.x) * 4;   // 2*128*4096 total
  f32x4 s = {0.f, 0.f, 0.f, 0.f};
#pragma unroll
  for (int ks = 0; ks < 8; ++ks) {
    f32x4 v = *(const f32x4*)(part + (size_t)ks * (2 * CC * L) + idx);
#pragma unroll
    for (int e = 0; e < 4; ++e) s[e] += v[e];
  }
  int p = idx & (L - 1);
  int u = p >> 6, vv = p & 63;
  f32x4 o;
#pragma unroll
  for (int e = 0; e < 4; ++e) o[e] = (u < 63 && (vv + e) < 63) ? s[e] * 0.25f : 0.f;
  *(f32x4*)(out + idx) = o;
}

extern "C" void kernel_launch(void* const* d_in, const int* in_sizes, int n_in,
                              void* d_out, int out_size, void* d_ws, size_t ws_size,
                              hipStream_t stream) {
  const float* f = (const float*)d_in[0];
  const float* b = (const float*)d_in[1];
  const float* mask = (const float*)d_in[2];
  float* out = (float*)d_out;
  char* ws = (char*)d_ws;

  f16* PT    = (f16*)(ws + 0);             // 67,108,864
  f16* S     = (f16*)(ws + 67108864);      // 67,108,864
  f16* bm    = (f16*)(ws + 134217728);     // 8,388,608
  float* pmP = (float*)(ws + 142606336);   // 16,777,216
  float* pl  = (float*)(ws + 159383552);   // 16,777,216
  float* part= (float*)(ws + 176160768);   // 33,554,432 (8 ks-splits)
  float* mmv = (float*)(ws + 209715200);   // 16,384
  float* Mq  = (float*)(ws + 209731584);   // 32,768
  float* iLq = (float*)(ws + 209764352);   // 32,768
  f16* bT    = (f16*)(ws + 209797120);     // 2,097,152
  f16* fT    = (f16*)(ws + 211894272);     // 2,097,152
  float* ssq = (float*)(ws + 213991424);   // 32,768
  float* invn= (float*)(ws + 214024192);   // 32,768
  f16* zp    = (f16*)(ws + 214056960);     // 64
  float* zcnt= (float*)(ws + 214057088);   // 2,048

  k_repack<<<dim3(64, 4), dim3(256), 0, stream>>>(b, f, bT, fT, zp, ssq);
  k_norm<<<dim3(32), dim3(256), 0, stream>>>(ssq, invn);
  k_prep_bm<<<dim3(2048), dim3(256), 0, stream>>>(b, bm);
  k_prep_mm<<<dim3(16), dim3(256), 0, stream>>>(mask, mmv, zcnt);
  k_gemm_scores<<<dim3(32, 32, 2), dim3(256), 0, stream>>>(bT, fT, invn, zp, S);
  k_fuse_stats<<<dim3(8, 128, 2), dim3(256), 0, stream>>>(S, mmv, PT, pmP, pl);
  k_fuse_stats_edge<<<dim3(512, 2), dim3(256), 0, stream>>>(S, mmv, PT, pmP, pl);
  k_softmax_reduce<<<dim3(128), dim3(256), 0, stream>>>(pmP, pl, zcnt, Mq, iLq);
  k_agg<<<dim3(64, 8, 2), dim3(512), 0, stream>>>(PT, pmP, Mq, iLq, bm, part);
  k_agg_reduce<<<dim3(1024), dim3(256), 0, stream>>>(part, out);
}